// Round 12
// baseline (344.568 us; speedup 1.0000x reference)
//
#include <hip/hip_runtime.h>

#define HW 4096
typedef __bf16 bf16_t;
typedef _Float16 f16_t;
typedef __bf16 bf16x8 __attribute__((ext_vector_type(8)));
typedef float  f32x4  __attribute__((ext_vector_type(4)));
typedef unsigned int u32;

__device__ __forceinline__ void gld_lds16(const void* g, void* l) {
    __builtin_amdgcn_global_load_lds(
        (const __attribute__((address_space(1))) u32*)g,
        (__attribute__((address_space(3))) u32*)l, 16, 0, 0);
}

// ---------------------------------------------------------------------------
// Weight prep: OIHW fp32 -> [tap][co(COPAD)][ci] bf16 (co>=COTOT zero-padded).
// ---------------------------------------------------------------------------
__global__ void prep_w(const float* __restrict__ w0, const float* __restrict__ w1,
                       bf16_t* __restrict__ out, int CIN, int CO0, int COTOT, int COPAD)
{
    int idx = blockIdx.x * 256 + threadIdx.x;
    if (idx >= COPAD * CIN) return;
    int co = idx / CIN, ci = idx % CIN;
    #pragma unroll
    for (int tap = 0; tap < 9; ++tap) {
        float v = 0.f;
        if (co < CO0)        v = w0[((size_t)co * CIN + ci) * 9 + tap];
        else if (co < COTOT) v = w1[((size_t)(co - CO0) * CIN + ci) * 9 + tap];
        out[((size_t)tap * COPAD + co) * CIN + ci] = (bf16_t)v;
    }
}

// ---------------------------------------------------------------------------
// NCHW fp32 -> zero-padded (66x66) NHWC bf16. Borders pre-zeroed by memset.
// ---------------------------------------------------------------------------
__global__ __launch_bounds__(256) void pad_nchw_to_nhwc(
    const float* __restrict__ in, bf16_t* __restrict__ out, int C)
{
    const int y = blockIdx.x, ct = blockIdx.y, img = blockIdx.z;
    const int tid = threadIdx.x;
    __shared__ float t[64][65];

    int c = tid >> 2, x0 = (tid & 3) * 16;
    const float* srcc = in + ((size_t)img * C + ct * 64 + c) * HW + y * 64 + x0;
    #pragma unroll
    for (int j = 0; j < 4; ++j) {
        float4 v = *(const float4*)&srcc[j * 4];
        t[c][x0 + j * 4 + 0] = v.x; t[c][x0 + j * 4 + 1] = v.y;
        t[c][x0 + j * 4 + 2] = v.z; t[c][x0 + j * 4 + 3] = v.w;
    }
    __syncthreads();
    int x = tid >> 2, cg = (tid & 3) * 16;
    bf16_t tmp[16];
    #pragma unroll
    for (int j = 0; j < 16; ++j) tmp[j] = (bf16_t)t[cg + j][x];
    bf16_t* dst = &out[((size_t)img * 4356 + (size_t)((y + 1) * 66 + (x + 1))) * C + ct * 64 + cg];
    *(bf16x8*)dst       = *(bf16x8*)&tmp[0];
    *((bf16x8*)dst + 1) = *(bf16x8*)&tmp[8];
}

// ---------------------------------------------------------------------------
// Tap-stationary implicit-GEMM 3x3 conv, bf16 MFMA, async global_load_lds.
// R12: generic ROWS (output rows per tile). Tile = ROWS*64 pixels x 64 cout,
// 4 waves (2 pix-halves x 2 co-halves), acc[2*ROWS][2].
// ROWS=2: LDS 50.2 KB -> 3 blocks/CU.  ROWS=4: LDS 67 KB -> 2 blocks/CU,
// 2x MFMA per phase, half the barriers (used for the value conv).
// MODE 0: -> value NHWC bf16, +bias, *!mask
// MODE 1: -> offattn f16 [n][4096][288] (co<192 bias0 else bias1; COPAD=320)
// MODE 2: swapped operands -> d_out NCHW f32 (+bias)
// ---------------------------------------------------------------------------
template<int CIN, int MODE, int ROWS>
__global__ __launch_bounds__(256) void mfma_conv(
    const bf16_t* __restrict__ Apad,   // [img][66*66][CIN]
    const bf16_t* __restrict__ Wprep,  // [9][COPAD][CIN]
    const float* __restrict__ bias0,
    const float* __restrict__ bias1,
    const unsigned char* __restrict__ mask,
    void* __restrict__ outp)
{
    constexpr int NCHUNK = CIN / 64;
    constexpr int COPAD = (MODE == 1) ? 320 : 256;
    constexpr int MROWS = ROWS / 2;     // rows per wave pixel-half
    constexpr int NM    = 2 * ROWS;     // MFMA m-tiles per wave
    constexpr int NQA   = (ROWS + 2) * 528;   // A-patch 16B-quads

    const int nbx = gridDim.x, gy = gridDim.y;
    const int nwg = nbx * gy * gridDim.z;
    const int pb = blockIdx.x + nbx * (blockIdx.y + gy * blockIdx.z);
    const int lb = (pb & 7) * (nwg >> 3) + (pb >> 3);
    const int bx  = lb % nbx;
    const int by  = (lb / nbx) % gy;
    const int img = lb / (nbx * gy);

    const int tid = threadIdx.x;
    const int l = tid & 63;
    const int w = tid >> 6;
    const int wm = w >> 1, wn = w & 1;
    const int y0 = bx * ROWS;
    const int cobase = by * 64;

    __shared__ bf16_t ldsA[(ROWS + 2) * 66 * 64];
    __shared__ bf16_t ldsB[2][64 * 64];

    const bf16_t* Aimg = Apad + (size_t)img * (66 * 66) * CIN;

    f32x4 acc[NM][2];
    #pragma unroll
    for (int m = 0; m < NM; ++m)
        #pragma unroll
        for (int n = 0; n < 2; ++n) acc[m][n] = (f32x4){0.f, 0.f, 0.f, 0.f};

    auto stageA = [&](int ci0) {
        #pragma unroll
        for (int i = 0; i < (NQA + 255) / 256; ++i) {
            int s = i * 256 + tid;
            if ((i + 1) * 256 <= NQA || s < NQA) {
                int row = s / 528;
                int rem = s - row * 528;
                int col = rem >> 3, qs = rem & 7;
                int qsrc = qs ^ (col & 7);
                const bf16_t* src = Aimg + ((size_t)((y0 + row) * 66 + col)) * CIN + ci0 + qsrc * 8;
                gld_lds16(src, &ldsA[(i * 256 + w * 64) * 8]);
            }
        }
    };
    auto stageB = [&](int tap, int ci0, int bufsel) {
        #pragma unroll
        for (int i = 0; i < 2; ++i) {
            int s = (w * 2 + i) * 64 + l;
            int r = s >> 3, qs = s & 7;
            int qsrc = qs ^ (r & 7);
            const bf16_t* src = Wprep + ((size_t)tap * COPAD + cobase + r) * CIN + ci0 + qsrc * 8;
            gld_lds16(src, &ldsB[bufsel][(w * 2 + i) * 512]);
        }
    };

    auto rdA = [&](int dy, int dx, int m, int kk) -> bf16x8 {
        int row = wm * MROWS + (m >> 2) + dy;
        int col = (m & 3) * 16 + (l & 15) + dx;
        int kq = kk * 4 + (l >> 4);
        float4 v = *(const float4*)&ldsA[(row * 66 + col) * 64 + ((kq ^ (col & 7)) * 8)];
        return __builtin_bit_cast(bf16x8, v);
    };
    auto rdB = [&](int bufsel, int n, int kk) -> bf16x8 {
        int r = wn * 32 + n * 16 + (l & 15);
        int kq = kk * 4 + (l >> 4);
        float4 v = *(const float4*)&ldsB[bufsel][r * 64 + ((kq ^ (r & 7)) * 8)];
        return __builtin_bit_cast(bf16x8, v);
    };

    for (int chunk = 0; chunk < NCHUNK; ++chunk) {
        const int ci0 = chunk * 64;
        stageA(ci0);
        stageB(0, ci0, 0);
        __syncthreads();

        int buf = 0;
        for (int tap = 0; tap < 9; ++tap) {
            const int dy = tap / 3, dx = tap % 3;
            if (tap < 8) stageB(tap + 1, ci0, buf ^ 1);
            #pragma unroll
            for (int kk = 0; kk < 2; ++kk) {
                bf16x8 a[NM];
                #pragma unroll
                for (int m = 0; m < NM; ++m) a[m] = rdA(dy, dx, m, kk);
                bf16x8 b0 = rdB(buf, 0, kk), b1 = rdB(buf, 1, kk);
                #pragma unroll
                for (int m = 0; m < NM; ++m) {
                    if constexpr (MODE == 2) {
                        acc[m][0] = __builtin_amdgcn_mfma_f32_16x16x32_bf16(b0, a[m], acc[m][0], 0, 0, 0);
                        acc[m][1] = __builtin_amdgcn_mfma_f32_16x16x32_bf16(b1, a[m], acc[m][1], 0, 0, 0);
                    } else {
                        acc[m][0] = __builtin_amdgcn_mfma_f32_16x16x32_bf16(a[m], b0, acc[m][0], 0, 0, 0);
                        acc[m][1] = __builtin_amdgcn_mfma_f32_16x16x32_bf16(a[m], b1, acc[m][1], 0, 0, 0);
                    }
                }
            }
            __syncthreads();
            buf ^= 1;
        }
    }

    #pragma unroll
    for (int m = 0; m < NM; ++m)
        #pragma unroll
        for (int n = 0; n < 2; ++n) {
            f32x4 fr = acc[m][n];
            if constexpr (MODE == 2) {
                int co  = cobase + wn * 32 + n * 16 + (l >> 4) * 4;
                int pix = bx * (ROWS * 64) + wm * (MROWS * 64) + (m >> 2) * 64 + (m & 3) * 16 + (l & 15);
                float* op = (float*)outp;
                #pragma unroll
                for (int r = 0; r < 4; ++r)
                    op[((size_t)img * 256 + co + r) * HW + pix] = fr[r] + bias0[co + r];
            } else {
                int pix = bx * (ROWS * 64) + wm * (MROWS * 64) + (m >> 2) * 64 + (m & 3) * 16 + (l >> 4) * 4;
                int co  = cobase + wn * 32 + n * 16 + (l & 15);
                if constexpr (MODE == 0) {
                    bf16_t* op = (bf16_t*)outp;
                    float bv = bias0[co];
                    #pragma unroll
                    for (int r = 0; r < 4; ++r) {
                        int p = pix + r;
                        float vv = fr[r] + bv;
                        if (mask[(size_t)img * HW + p]) vv = 0.f;
                        op[((size_t)img * HW + p) * 256 + co] = (bf16_t)vv;
                    }
                } else {
                    if (co < 288) {
                        f16_t* op = (f16_t*)outp;
                        float bv = (co < 192) ? bias0[co] : bias1[co - 192];
                        #pragma unroll
                        for (int r = 0; r < 4; ++r)
                            op[((size_t)img * HW + pix + r) * 288 + co] = (f16_t)(fr[r] + bv);
                    }
                }
            }
        }
}

// ---------------------------------------------------------------------------
// Deformable sampling core, vectorized gathers, explicit 2-deep pipeline.
// (unchanged from R9)
// ---------------------------------------------------------------------------
__global__ __launch_bounds__(256) void msda_core_kernel(
    const bf16_t* __restrict__ value,
    const f16_t* __restrict__ offattn,
    const float* __restrict__ refp,
    bf16_t* __restrict__ outpad)
{
    constexpr int QB = 16;
    const int n    = blockIdx.y;
    const int q0   = blockIdx.x * QB;
    const int tid  = threadIdx.x;
    const int oct  = tid & 31;
    const int qsub = tid >> 5;
    const int hd   = oct >> 2;

    __shared__ float s_oa[QB][288];
    __shared__ float s_ref[QB][6];
    __shared__ float s_aw[QB][96];

    for (int e = tid; e < QB * 288; e += 256) {
        int q = e / 288, c = e % 288;
        s_oa[q][c] = (float)offattn[((size_t)n * HW + q0 + q) * 288 + c];
    }
    if (tid < QB * 6) {
        int q = tid / 6, r = tid % 6;
        s_ref[q][r] = refp[((size_t)n * HW + q0 + q) * 6 + r];
    }
    __syncthreads();

    if (tid < QB * 8) {
        int q = tid >> 3, h = tid & 7;
        const float* a = &s_oa[q][192 + h * 12];
        float mx = a[0];
        #pragma unroll
        for (int k = 1; k < 12; ++k) mx = fmaxf(mx, a[k]);
        float e[12]; float sum = 0.f;
        #pragma unroll
        for (int k = 0; k < 12; ++k) { e[k] = __expf(a[k] - mx); sum += e[k]; }
        float inv = 1.f / sum;
        #pragma unroll
        for (int k = 0; k < 12; ++k) s_aw[q][h * 12 + k] = e[k] * inv;
    }
    __syncthreads();

    float acc[2][8];
    #pragma unroll
    for (int qi = 0; qi < 2; ++qi)
        #pragma unroll
        for (int j = 0; j < 8; ++j) acc[qi][j] = 0.f;

    const bf16x8 zero8 = {};
    const size_t vstride = (size_t)HW * 256;
    const bf16_t* vimg = value + (size_t)(n * 3) * vstride + oct * 8;

    auto issue = [&](int pt, bf16x8 (&g)[2][4], float (&wt)[2][4]) {
        const int ll = pt >> 2, p = pt & 3;
        const bf16_t* vbase = vimg + (size_t)ll * vstride;
        #pragma unroll
        for (int qi = 0; qi < 2; ++qi) {
            const int qq = qsub * 2 + qi;
            const int idx = hd * 12 + ll * 4 + p;
            float x = s_ref[qq][ll * 2 + 0] * 64.f - 0.5f + s_oa[qq][idx * 2 + 0];
            float y = s_ref[qq][ll * 2 + 1] * 64.f - 0.5f + s_oa[qq][idx * 2 + 1];
            float aw = s_aw[qq][idx];
            float xf = floorf(x), yf = floorf(y);
            float lx = x - xf, ly = y - yf;
            int xi = (int)xf, yi = (int)yf;
            wt[qi][0] = (1.f - lx) * (1.f - ly) * aw;
            wt[qi][1] = lx * (1.f - ly) * aw;
            wt[qi][2] = (1.f - lx) * ly * aw;
            wt[qi][3] = lx * ly * aw;
            bool vx0 = (xi >= 0) && (xi < 64);
            bool vx1 = (xi + 1 >= 0) && (xi + 1 < 64);
            bool vy0 = (yi >= 0) && (yi < 64);
            bool vy1 = (yi + 1 >= 0) && (yi + 1 < 64);
            g[qi][0] = (vy0 && vx0) ? *(const bf16x8*)(vbase + (size_t)(yi * 64 + xi) * 256)           : zero8;
            g[qi][1] = (vy0 && vx1) ? *(const bf16x8*)(vbase + (size_t)(yi * 64 + xi + 1) * 256)       : zero8;
            g[qi][2] = (vy1 && vx0) ? *(const bf16x8*)(vbase + (size_t)((yi + 1) * 64 + xi) * 256)     : zero8;
            g[qi][3] = (vy1 && vx1) ? *(const bf16x8*)(vbase + (size_t)((yi + 1) * 64 + xi + 1) * 256) : zero8;
        }
    };
    auto consume = [&](bf16x8 (&g)[2][4], float (&wt)[2][4]) {
        #pragma unroll
        for (int qi = 0; qi < 2; ++qi)
            #pragma unroll
            for (int j = 0; j < 8; ++j)
                acc[qi][j] += wt[qi][0] * (float)g[qi][0][j] + wt[qi][1] * (float)g[qi][1][j]
                            + wt[qi][2] * (float)g[qi][2][j] + wt[qi][3] * (float)g[qi][3][j];
    };

    bf16x8 gA[2][4], gB[2][4];
    float  wA[2][4], wB[2][4];
    issue(0, gA, wA);
    #pragma unroll 1
    for (int pt = 0; pt < 12; pt += 2) {
        if (pt + 1 < 12) issue(pt + 1, gB, wB);
        consume(gA, wA);
        if (pt + 2 < 12) issue(pt + 2, gA, wA);
        consume(gB, wB);
    }

    #pragma unroll
    for (int qi = 0; qi < 2; ++qi) {
        const int qq = qsub * 2 + qi;
        int pix = q0 + qq;
        int pp = ((pix >> 6) + 1) * 66 + (pix & 63) + 1;
        bf16_t tmp[8];
        #pragma unroll
        for (int j = 0; j < 8; ++j) tmp[j] = (bf16_t)acc[qi][j];
        *(bf16x8*)&outpad[((size_t)n * 4356 + pp) * 256 + oct * 8] = *(bf16x8*)tmp;
    }
}

extern "C" void kernel_launch(void* const* d_in, const int* in_sizes, int n_in,
                              void* d_out, int out_size, void* d_ws, size_t ws_size,
                              hipStream_t stream) {
    const float* query   = (const float*)d_in[0];
    const float* refp    = (const float*)d_in[1];
    const float* inflat  = (const float*)d_in[2];
    const unsigned char* mask = (const unsigned char*)d_in[5];
    const float* w_value = (const float*)d_in[6];
    const float* b_value = (const float*)d_in[7];
    const float* w_off   = (const float*)d_in[8];
    const float* b_off   = (const float*)d_in[9];
    const float* w_attn  = (const float*)d_in[10];
    const float* b_attn  = (const float*)d_in[11];
    const float* w_out   = (const float*)d_in[12];
    const float* b_out   = (const float*)d_in[13];

    char* ws = (char*)d_ws;
    bf16_t* A_val  = (bf16_t*)ws;  ws += (size_t)12 * 4356 * 256 * 2;  // 26.76 MB
    bf16_t* A_qry  = (bf16_t*)ws;  ws += (size_t)4 * 4356 * 768 * 2;   // 26.76 MB
    bf16_t* A_core = (bf16_t*)ws;  ws += (size_t)4 * 4356 * 256 * 2;   // 8.92 MB
    size_t pad_bytes = (size_t)(12 * 4356 * 256 + 4 * 4356 * 768 + 4 * 4356 * 256) * 2;
    bf16_t* W_val  = (bf16_t*)ws;  ws += (size_t)9 * 256 * 256 * 2;
    bf16_t* W_off  = (bf16_t*)ws;  ws += (size_t)9 * 320 * 768 * 2;    // COPAD=320
    bf16_t* W_out  = (bf16_t*)ws;  ws += (size_t)9 * 256 * 256 * 2;
    f16_t*  offattn = (f16_t*)ws;  ws += (size_t)4 * 4096 * 288 * 2;   // 9.44 MB
    bf16_t* value  = A_qry;  // reuse: off-conv consumes A_qry before value conv writes
    // total ws ~ 79.6 MiB (< 86 MiB proven available by round 1)

    hipMemsetAsync(d_ws, 0, pad_bytes, stream);

    prep_w<<<(256 * 256 + 255) / 256, 256, 0, stream>>>(w_value, nullptr, W_val, 256, 256, 256, 256);
    prep_w<<<(320 * 768 + 255) / 256, 256, 0, stream>>>(w_off, w_attn, W_off, 768, 192, 288, 320);
    prep_w<<<(256 * 256 + 255) / 256, 256, 0, stream>>>(w_out, nullptr, W_out, 256, 256, 256, 256);

    pad_nchw_to_nhwc<<<dim3(64, 4, 12), 256, 0, stream>>>(inflat, A_val, 256);
    pad_nchw_to_nhwc<<<dim3(64, 12, 4), 256, 0, stream>>>(query,  A_qry, 768);

    mfma_conv<768, 1, 2><<<dim3(32, 5, 4),  256, 0, stream>>>(A_qry, W_off, b_off, b_attn, nullptr, offattn);
    mfma_conv<256, 0, 4><<<dim3(16, 4, 12), 256, 0, stream>>>(A_val, W_val, b_value, nullptr, mask, value);

    msda_core_kernel<<<dim3(HW / 16, 4), 256, 0, stream>>>(value, offattn, refp, A_core);

    mfma_conv<256, 2, 2><<<dim3(32, 4, 4),  256, 0, stream>>>(A_core, W_out, b_out, nullptr, nullptr, d_out);
}

// Round 13
// 269.689 us; speedup vs baseline: 1.2777x; 1.2777x over previous
//
#include <hip/hip_runtime.h>

#define HW 4096
typedef __bf16 bf16_t;
typedef _Float16 f16_t;
typedef __bf16 bf16x8 __attribute__((ext_vector_type(8)));
typedef float  f32x4  __attribute__((ext_vector_type(4)));
typedef unsigned int u32;

__device__ __forceinline__ void gld_lds16(const void* g, void* l) {
    __builtin_amdgcn_global_load_lds(
        (const __attribute__((address_space(1))) u32*)g,
        (__attribute__((address_space(3))) u32*)l, 16, 0, 0);
}

// ---------------------------------------------------------------------------
// Weight prep: OIHW fp32 -> [tap][co(COPAD)][ci] bf16 (co>=COTOT zero-padded).
// ---------------------------------------------------------------------------
__global__ void prep_w(const float* __restrict__ w0, const float* __restrict__ w1,
                       bf16_t* __restrict__ out, int CIN, int CO0, int COTOT, int COPAD)
{
    int idx = blockIdx.x * 256 + threadIdx.x;
    if (idx >= COPAD * CIN) return;
    int co = idx / CIN, ci = idx % CIN;
    #pragma unroll
    for (int tap = 0; tap < 9; ++tap) {
        float v = 0.f;
        if (co < CO0)        v = w0[((size_t)co * CIN + ci) * 9 + tap];
        else if (co < COTOT) v = w1[((size_t)(co - CO0) * CIN + ci) * 9 + tap];
        out[((size_t)tap * COPAD + co) * CIN + ci] = (bf16_t)v;
    }
}

// ---------------------------------------------------------------------------
// NCHW fp32 -> zero-padded (66x66) NHWC bf16. Borders pre-zeroed by memset.
// ---------------------------------------------------------------------------
__global__ __launch_bounds__(256) void pad_nchw_to_nhwc(
    const float* __restrict__ in, bf16_t* __restrict__ out, int C)
{
    const int y = blockIdx.x, ct = blockIdx.y, img = blockIdx.z;
    const int tid = threadIdx.x;
    __shared__ float t[64][65];

    int c = tid >> 2, x0 = (tid & 3) * 16;
    const float* srcc = in + ((size_t)img * C + ct * 64 + c) * HW + y * 64 + x0;
    #pragma unroll
    for (int j = 0; j < 4; ++j) {
        float4 v = *(const float4*)&srcc[j * 4];
        t[c][x0 + j * 4 + 0] = v.x; t[c][x0 + j * 4 + 1] = v.y;
        t[c][x0 + j * 4 + 2] = v.z; t[c][x0 + j * 4 + 3] = v.w;
    }
    __syncthreads();
    int x = tid >> 2, cg = (tid & 3) * 16;
    bf16_t tmp[16];
    #pragma unroll
    for (int j = 0; j < 16; ++j) tmp[j] = (bf16_t)t[cg + j][x];
    bf16_t* dst = &out[((size_t)img * 4356 + (size_t)((y + 1) * 66 + (x + 1))) * C + ct * 64 + cg];
    *(bf16x8*)dst       = *(bf16x8*)&tmp[0];
    *((bf16x8*)dst + 1) = *(bf16x8*)&tmp[8];
}

// ---------------------------------------------------------------------------
// Tap-stationary implicit-GEMM 3x3 conv, bf16 MFMA, async global_load_lds.
// R13: exact R11 structure (proven 275us); ONLY change: COPAD 384->320 for
// MODE 1 (pure work reduction; R12's ROWS-template rewrite regressed and is
// fully reverted).
// Tile 128 pixels x 64 cout (acc[4][2]); LDS 49.8 KB -> 3 blocks/CU.
// MODE 0: -> value NHWC bf16, +bias, *!mask
// MODE 1: -> offattn f16 [n][4096][288] (co<192 bias0 else bias1; COPAD=320)
// MODE 2: swapped operands -> d_out NCHW f32 (+bias)
// ---------------------------------------------------------------------------
template<int CIN, int MODE>
__global__ __launch_bounds__(256) void mfma_conv(
    const bf16_t* __restrict__ Apad,   // [img][66*66][CIN]
    const bf16_t* __restrict__ Wprep,  // [9][COPAD][CIN]
    const float* __restrict__ bias0,
    const float* __restrict__ bias1,
    const unsigned char* __restrict__ mask,
    void* __restrict__ outp)
{
    constexpr int NCHUNK = CIN / 64;
    constexpr int COPAD = (MODE == 1) ? 320 : 256;

    const int gy = gridDim.y;
    const int nwg = 32 * gy * gridDim.z;
    const int pb = blockIdx.x + 32 * (blockIdx.y + gy * blockIdx.z);
    const int lb = (pb & 7) * (nwg >> 3) + (pb >> 3);
    const int bx  = lb & 31;
    const int by  = (lb >> 5) % gy;
    const int img = lb / (32 * gy);

    const int tid = threadIdx.x;
    const int l = tid & 63;
    const int w = tid >> 6;
    const int wm = w >> 1, wn = w & 1;   // pixel-half, co-half (32 co each)
    const int y0 = bx * 2;
    const int cobase = by * 64;

    __shared__ bf16_t ldsA[4 * 66 * 64];     // 33.8 KB
    __shared__ bf16_t ldsB[2][64 * 64];      // 16 KB

    const bf16_t* Aimg = Apad + (size_t)img * (66 * 66) * CIN;

    f32x4 acc[4][2];
    #pragma unroll
    for (int m = 0; m < 4; ++m)
        #pragma unroll
        for (int n = 0; n < 2; ++n) acc[m][n] = (f32x4){0.f, 0.f, 0.f, 0.f};

    auto stageA = [&](int ci0) {
        for (int i = w; i < 33; i += 4) {
            int s = i * 64 + l;
            int row = s / 528;
            int rem = s - row * 528;
            int col = rem >> 3, qs = rem & 7;
            int qsrc = qs ^ (col & 7);
            const bf16_t* src = Aimg + ((size_t)((y0 + row) * 66 + col)) * CIN + ci0 + qsrc * 8;
            gld_lds16(src, &ldsA[i * 512]);
        }
    };
    // B tile 64co x 64ci = 512 quads; 2 per thread
    auto stageB = [&](int tap, int ci0, int bufsel) {
        #pragma unroll
        for (int i = 0; i < 2; ++i) {
            int s = (w * 2 + i) * 64 + l;
            int r = s >> 3, qs = s & 7;
            int qsrc = qs ^ (r & 7);
            const bf16_t* src = Wprep + ((size_t)tap * COPAD + cobase + r) * CIN + ci0 + qsrc * 8;
            gld_lds16(src, &ldsB[bufsel][(w * 2 + i) * 512]);
        }
    };

    auto rdA = [&](int dy, int dx, int m, int kk) -> bf16x8 {
        int col = m * 16 + (l & 15) + dx;
        int kq = kk * 4 + (l >> 4);
        float4 v = *(const float4*)&ldsA[((wm + dy) * 66 + col) * 64 + ((kq ^ (col & 7)) * 8)];
        return __builtin_bit_cast(bf16x8, v);
    };
    auto rdB = [&](int bufsel, int n, int kk) -> bf16x8 {
        int r = wn * 32 + n * 16 + (l & 15);
        int kq = kk * 4 + (l >> 4);
        float4 v = *(const float4*)&ldsB[bufsel][r * 64 + ((kq ^ (r & 7)) * 8)];
        return __builtin_bit_cast(bf16x8, v);
    };

    for (int chunk = 0; chunk < NCHUNK; ++chunk) {
        const int ci0 = chunk * 64;
        stageA(ci0);
        stageB(0, ci0, 0);
        __syncthreads();

        int buf = 0;
        for (int tap = 0; tap < 9; ++tap) {
            const int dy = tap / 3, dx = tap % 3;
            if (tap < 8) stageB(tap + 1, ci0, buf ^ 1);
            #pragma unroll
            for (int kk = 0; kk < 2; ++kk) {
                bf16x8 a0 = rdA(dy, dx, 0, kk), a1 = rdA(dy, dx, 1, kk);
                bf16x8 a2 = rdA(dy, dx, 2, kk), a3 = rdA(dy, dx, 3, kk);
                bf16x8 b0 = rdB(buf, 0, kk), b1 = rdB(buf, 1, kk);
                #pragma unroll
                for (int m = 0; m < 4; ++m) {
                    bf16x8 am = (m == 0) ? a0 : (m == 1) ? a1 : (m == 2) ? a2 : a3;
                    if constexpr (MODE == 2) {
                        acc[m][0] = __builtin_amdgcn_mfma_f32_16x16x32_bf16(b0, am, acc[m][0], 0, 0, 0);
                        acc[m][1] = __builtin_amdgcn_mfma_f32_16x16x32_bf16(b1, am, acc[m][1], 0, 0, 0);
                    } else {
                        acc[m][0] = __builtin_amdgcn_mfma_f32_16x16x32_bf16(am, b0, acc[m][0], 0, 0, 0);
                        acc[m][1] = __builtin_amdgcn_mfma_f32_16x16x32_bf16(am, b1, acc[m][1], 0, 0, 0);
                    }
                }
            }
            __syncthreads();
            buf ^= 1;
        }
    }

    #pragma unroll
    for (int m = 0; m < 4; ++m)
        #pragma unroll
        for (int n = 0; n < 2; ++n) {
            f32x4 fr = acc[m][n];
            if constexpr (MODE == 2) {
                int co  = cobase + wn * 32 + n * 16 + (l >> 4) * 4;
                int pix = bx * 128 + wm * 64 + m * 16 + (l & 15);
                float* op = (float*)outp;
                #pragma unroll
                for (int r = 0; r < 4; ++r)
                    op[((size_t)img * 256 + co + r) * HW + pix] = fr[r] + bias0[co + r];
            } else {
                int pix = bx * 128 + wm * 64 + m * 16 + (l >> 4) * 4;
                int co  = cobase + wn * 32 + n * 16 + (l & 15);
                if constexpr (MODE == 0) {
                    bf16_t* op = (bf16_t*)outp;
                    float bv = bias0[co];
                    #pragma unroll
                    for (int r = 0; r < 4; ++r) {
                        int p = pix + r;
                        float vv = fr[r] + bv;
                        if (mask[(size_t)img * HW + p]) vv = 0.f;
                        op[((size_t)img * HW + p) * 256 + co] = (bf16_t)vv;
                    }
                } else {
                    if (co < 288) {
                        f16_t* op = (f16_t*)outp;
                        float bv = (co < 192) ? bias0[co] : bias1[co - 192];
                        #pragma unroll
                        for (int r = 0; r < 4; ++r)
                            op[((size_t)img * HW + pix + r) * 288 + co] = (f16_t)(fr[r] + bv);
                    }
                }
            }
        }
}

// ---------------------------------------------------------------------------
// Deformable sampling core, vectorized gathers, explicit 2-deep pipeline.
// (unchanged from R9)
// ---------------------------------------------------------------------------
__global__ __launch_bounds__(256) void msda_core_kernel(
    const bf16_t* __restrict__ value,
    const f16_t* __restrict__ offattn,
    const float* __restrict__ refp,
    bf16_t* __restrict__ outpad)
{
    constexpr int QB = 16;
    const int n    = blockIdx.y;
    const int q0   = blockIdx.x * QB;
    const int tid  = threadIdx.x;
    const int oct  = tid & 31;
    const int qsub = tid >> 5;
    const int hd   = oct >> 2;

    __shared__ float s_oa[QB][288];
    __shared__ float s_ref[QB][6];
    __shared__ float s_aw[QB][96];

    for (int e = tid; e < QB * 288; e += 256) {
        int q = e / 288, c = e % 288;
        s_oa[q][c] = (float)offattn[((size_t)n * HW + q0 + q) * 288 + c];
    }
    if (tid < QB * 6) {
        int q = tid / 6, r = tid % 6;
        s_ref[q][r] = refp[((size_t)n * HW + q0 + q) * 6 + r];
    }
    __syncthreads();

    if (tid < QB * 8) {
        int q = tid >> 3, h = tid & 7;
        const float* a = &s_oa[q][192 + h * 12];
        float mx = a[0];
        #pragma unroll
        for (int k = 1; k < 12; ++k) mx = fmaxf(mx, a[k]);
        float e[12]; float sum = 0.f;
        #pragma unroll
        for (int k = 0; k < 12; ++k) { e[k] = __expf(a[k] - mx); sum += e[k]; }
        float inv = 1.f / sum;
        #pragma unroll
        for (int k = 0; k < 12; ++k) s_aw[q][h * 12 + k] = e[k] * inv;
    }
    __syncthreads();

    float acc[2][8];
    #pragma unroll
    for (int qi = 0; qi < 2; ++qi)
        #pragma unroll
        for (int j = 0; j < 8; ++j) acc[qi][j] = 0.f;

    const bf16x8 zero8 = {};
    const size_t vstride = (size_t)HW * 256;
    const bf16_t* vimg = value + (size_t)(n * 3) * vstride + oct * 8;

    auto issue = [&](int pt, bf16x8 (&g)[2][4], float (&wt)[2][4]) {
        const int ll = pt >> 2, p = pt & 3;
        const bf16_t* vbase = vimg + (size_t)ll * vstride;
        #pragma unroll
        for (int qi = 0; qi < 2; ++qi) {
            const int qq = qsub * 2 + qi;
            const int idx = hd * 12 + ll * 4 + p;
            float x = s_ref[qq][ll * 2 + 0] * 64.f - 0.5f + s_oa[qq][idx * 2 + 0];
            float y = s_ref[qq][ll * 2 + 1] * 64.f - 0.5f + s_oa[qq][idx * 2 + 1];
            float aw = s_aw[qq][idx];
            float xf = floorf(x), yf = floorf(y);
            float lx = x - xf, ly = y - yf;
            int xi = (int)xf, yi = (int)yf;
            wt[qi][0] = (1.f - lx) * (1.f - ly) * aw;
            wt[qi][1] = lx * (1.f - ly) * aw;
            wt[qi][2] = (1.f - lx) * ly * aw;
            wt[qi][3] = lx * ly * aw;
            bool vx0 = (xi >= 0) && (xi < 64);
            bool vx1 = (xi + 1 >= 0) && (xi + 1 < 64);
            bool vy0 = (yi >= 0) && (yi < 64);
            bool vy1 = (yi + 1 >= 0) && (yi + 1 < 64);
            g[qi][0] = (vy0 && vx0) ? *(const bf16x8*)(vbase + (size_t)(yi * 64 + xi) * 256)           : zero8;
            g[qi][1] = (vy0 && vx1) ? *(const bf16x8*)(vbase + (size_t)(yi * 64 + xi + 1) * 256)       : zero8;
            g[qi][2] = (vy1 && vx0) ? *(const bf16x8*)(vbase + (size_t)((yi + 1) * 64 + xi) * 256)     : zero8;
            g[qi][3] = (vy1 && vx1) ? *(const bf16x8*)(vbase + (size_t)((yi + 1) * 64 + xi + 1) * 256) : zero8;
        }
    };
    auto consume = [&](bf16x8 (&g)[2][4], float (&wt)[2][4]) {
        #pragma unroll
        for (int qi = 0; qi < 2; ++qi)
            #pragma unroll
            for (int j = 0; j < 8; ++j)
                acc[qi][j] += wt[qi][0] * (float)g[qi][0][j] + wt[qi][1] * (float)g[qi][1][j]
                            + wt[qi][2] * (float)g[qi][2][j] + wt[qi][3] * (float)g[qi][3][j];
    };

    bf16x8 gA[2][4], gB[2][4];
    float  wA[2][4], wB[2][4];
    issue(0, gA, wA);
    #pragma unroll 1
    for (int pt = 0; pt < 12; pt += 2) {
        if (pt + 1 < 12) issue(pt + 1, gB, wB);
        consume(gA, wA);
        if (pt + 2 < 12) issue(pt + 2, gA, wA);
        consume(gB, wB);
    }

    #pragma unroll
    for (int qi = 0; qi < 2; ++qi) {
        const int qq = qsub * 2 + qi;
        int pix = q0 + qq;
        int pp = ((pix >> 6) + 1) * 66 + (pix & 63) + 1;
        bf16_t tmp[8];
        #pragma unroll
        for (int j = 0; j < 8; ++j) tmp[j] = (bf16_t)acc[qi][j];
        *(bf16x8*)&outpad[((size_t)n * 4356 + pp) * 256 + oct * 8] = *(bf16x8*)tmp;
    }
}

extern "C" void kernel_launch(void* const* d_in, const int* in_sizes, int n_in,
                              void* d_out, int out_size, void* d_ws, size_t ws_size,
                              hipStream_t stream) {
    const float* query   = (const float*)d_in[0];
    const float* refp    = (const float*)d_in[1];
    const float* inflat  = (const float*)d_in[2];
    const unsigned char* mask = (const unsigned char*)d_in[5];
    const float* w_value = (const float*)d_in[6];
    const float* b_value = (const float*)d_in[7];
    const float* w_off   = (const float*)d_in[8];
    const float* b_off   = (const float*)d_in[9];
    const float* w_attn  = (const float*)d_in[10];
    const float* b_attn  = (const float*)d_in[11];
    const float* w_out   = (const float*)d_in[12];
    const float* b_out   = (const float*)d_in[13];

    char* ws = (char*)d_ws;
    bf16_t* A_val  = (bf16_t*)ws;  ws += (size_t)12 * 4356 * 256 * 2;  // 26.76 MB
    bf16_t* A_qry  = (bf16_t*)ws;  ws += (size_t)4 * 4356 * 768 * 2;   // 26.76 MB
    bf16_t* A_core = (bf16_t*)ws;  ws += (size_t)4 * 4356 * 256 * 2;   // 8.92 MB
    size_t pad_bytes = (size_t)(12 * 4356 * 256 + 4 * 4356 * 768 + 4 * 4356 * 256) * 2;
    bf16_t* W_val  = (bf16_t*)ws;  ws += (size_t)9 * 256 * 256 * 2;
    bf16_t* W_off  = (bf16_t*)ws;  ws += (size_t)9 * 320 * 768 * 2;    // COPAD=320
    bf16_t* W_out  = (bf16_t*)ws;  ws += (size_t)9 * 256 * 256 * 2;
    f16_t*  offattn = (f16_t*)ws;  ws += (size_t)4 * 4096 * 288 * 2;   // 9.44 MB
    bf16_t* value  = A_qry;  // reuse: off-conv consumes A_qry before value conv writes
    // total ws ~ 79.6 MiB (< 86 MiB proven available by round 1)

    hipMemsetAsync(d_ws, 0, pad_bytes, stream);

    prep_w<<<(256 * 256 + 255) / 256, 256, 0, stream>>>(w_value, nullptr, W_val, 256, 256, 256, 256);
    prep_w<<<(320 * 768 + 255) / 256, 256, 0, stream>>>(w_off, w_attn, W_off, 768, 192, 288, 320);
    prep_w<<<(256 * 256 + 255) / 256, 256, 0, stream>>>(w_out, nullptr, W_out, 256, 256, 256, 256);

    pad_nchw_to_nhwc<<<dim3(64, 4, 12), 256, 0, stream>>>(inflat, A_val, 256);
    pad_nchw_to_nhwc<<<dim3(64, 12, 4), 256, 0, stream>>>(query,  A_qry, 768);

    mfma_conv<768, 1><<<dim3(32, 5, 4),  256, 0, stream>>>(A_qry, W_off, b_off, b_attn, nullptr, offattn);
    mfma_conv<256, 0><<<dim3(32, 4, 12), 256, 0, stream>>>(A_val, W_val, b_value, nullptr, mask, value);

    msda_core_kernel<<<dim3(HW / 16, 4), 256, 0, stream>>>(value, offattn, refp, A_core);

    mfma_conv<256, 2><<<dim3(32, 4, 4),  256, 0, stream>>>(A_core, W_out, b_out, nullptr, nullptr, d_out);
}

// Round 14
// 263.015 us; speedup vs baseline: 1.3101x; 1.0254x over previous
//
#include <hip/hip_runtime.h>

#define HW 4096
typedef __bf16 bf16_t;
typedef _Float16 f16_t;
typedef __bf16 bf16x8 __attribute__((ext_vector_type(8)));
typedef float  f32x4  __attribute__((ext_vector_type(4)));
typedef unsigned int u32;

__device__ __forceinline__ void gld_lds16(const void* g, void* l) {
    __builtin_amdgcn_global_load_lds(
        (const __attribute__((address_space(1))) u32*)g,
        (__attribute__((address_space(3))) u32*)l, 16, 0, 0);
}

// ---------------------------------------------------------------------------
// Zero ONLY the border cells of a padded [imgs][66*66][C] buffer (260 cells
// per image: rows 0/65 full width, cols 0/65 rows 1..64). Interiors are
// fully overwritten every call; borders must read as 0 for conv halos.
// Replaces the 71MB full memset (~11us) with ~3.7MB of writes.
// ---------------------------------------------------------------------------
__global__ void zero_border(bf16_t* __restrict__ buf, int C)
{
    const int img = blockIdx.y;
    const int c8n = C >> 3;
    int idx = blockIdx.x * 256 + threadIdx.x;
    if (idx >= 260 * c8n) return;
    int cell = idx / c8n, c8 = idx % c8n;
    int row, col;
    if (cell < 66)       { row = 0;          col = cell; }
    else if (cell < 132) { row = 65;         col = cell - 66; }
    else if (cell < 196) { row = cell - 131; col = 0; }
    else                 { row = cell - 195; col = 65; }
    *(bf16x8*)&buf[((size_t)img * 4356 + row * 66 + col) * C + c8 * 8] = (bf16x8){};
}

// ---------------------------------------------------------------------------
// Weight prep: OIHW fp32 -> [tap][co(COPAD)][ci] bf16 (co>=COTOT zero-padded).
// ---------------------------------------------------------------------------
__global__ void prep_w(const float* __restrict__ w0, const float* __restrict__ w1,
                       bf16_t* __restrict__ out, int CIN, int CO0, int COTOT, int COPAD)
{
    int idx = blockIdx.x * 256 + threadIdx.x;
    if (idx >= COPAD * CIN) return;
    int co = idx / CIN, ci = idx % CIN;
    #pragma unroll
    for (int tap = 0; tap < 9; ++tap) {
        float v = 0.f;
        if (co < CO0)        v = w0[((size_t)co * CIN + ci) * 9 + tap];
        else if (co < COTOT) v = w1[((size_t)(co - CO0) * CIN + ci) * 9 + tap];
        out[((size_t)tap * COPAD + co) * CIN + ci] = (bf16_t)v;
    }
}

// ---------------------------------------------------------------------------
// NCHW fp32 -> zero-padded (66x66) NHWC bf16 (interior only).
// ---------------------------------------------------------------------------
__global__ __launch_bounds__(256) void pad_nchw_to_nhwc(
    const float* __restrict__ in, bf16_t* __restrict__ out, int C)
{
    const int y = blockIdx.x, ct = blockIdx.y, img = blockIdx.z;
    const int tid = threadIdx.x;
    __shared__ float t[64][65];

    int c = tid >> 2, x0 = (tid & 3) * 16;
    const float* srcc = in + ((size_t)img * C + ct * 64 + c) * HW + y * 64 + x0;
    #pragma unroll
    for (int j = 0; j < 4; ++j) {
        float4 v = *(const float4*)&srcc[j * 4];
        t[c][x0 + j * 4 + 0] = v.x; t[c][x0 + j * 4 + 1] = v.y;
        t[c][x0 + j * 4 + 2] = v.z; t[c][x0 + j * 4 + 3] = v.w;
    }
    __syncthreads();
    int x = tid >> 2, cg = (tid & 3) * 16;
    bf16_t tmp[16];
    #pragma unroll
    for (int j = 0; j < 16; ++j) tmp[j] = (bf16_t)t[cg + j][x];
    bf16_t* dst = &out[((size_t)img * 4356 + (size_t)((y + 1) * 66 + (x + 1))) * C + ct * 64 + cg];
    *(bf16x8*)dst       = *(bf16x8*)&tmp[0];
    *((bf16x8*)dst + 1) = *(bf16x8*)&tmp[8];
}

// ---------------------------------------------------------------------------
// Tap-stationary implicit-GEMM 3x3 conv, bf16 MFMA, async global_load_lds.
// R13 structure (proven); tile 128 pixels x 64 cout (acc[4][2]);
// LDS 49.8 KB -> 3 blocks/CU.
// MODE 0: -> value NHWC bf16, +bias, *!mask
// MODE 1: -> offattn f16 [n][4096][288] (co<192 bias0 else bias1; COPAD=320)
// MODE 2: swapped operands -> d_out NCHW f32 (+bias)
// ---------------------------------------------------------------------------
template<int CIN, int MODE>
__global__ __launch_bounds__(256) void mfma_conv(
    const bf16_t* __restrict__ Apad,   // [img][66*66][CIN]
    const bf16_t* __restrict__ Wprep,  // [9][COPAD][CIN]
    const float* __restrict__ bias0,
    const float* __restrict__ bias1,
    const unsigned char* __restrict__ mask,
    void* __restrict__ outp)
{
    constexpr int NCHUNK = CIN / 64;
    constexpr int COPAD = (MODE == 1) ? 320 : 256;

    const int gy = gridDim.y;
    const int nwg = 32 * gy * gridDim.z;
    const int pb = blockIdx.x + 32 * (blockIdx.y + gy * blockIdx.z);
    const int lb = (pb & 7) * (nwg >> 3) + (pb >> 3);
    const int bx  = lb & 31;
    const int by  = (lb >> 5) % gy;
    const int img = lb / (32 * gy);

    const int tid = threadIdx.x;
    const int l = tid & 63;
    const int w = tid >> 6;
    const int wm = w >> 1, wn = w & 1;   // pixel-half, co-half (32 co each)
    const int y0 = bx * 2;
    const int cobase = by * 64;

    __shared__ bf16_t ldsA[4 * 66 * 64];     // 33.8 KB
    __shared__ bf16_t ldsB[2][64 * 64];      // 16 KB

    const bf16_t* Aimg = Apad + (size_t)img * (66 * 66) * CIN;

    f32x4 acc[4][2];
    #pragma unroll
    for (int m = 0; m < 4; ++m)
        #pragma unroll
        for (int n = 0; n < 2; ++n) acc[m][n] = (f32x4){0.f, 0.f, 0.f, 0.f};

    auto stageA = [&](int ci0) {
        for (int i = w; i < 33; i += 4) {
            int s = i * 64 + l;
            int row = s / 528;
            int rem = s - row * 528;
            int col = rem >> 3, qs = rem & 7;
            int qsrc = qs ^ (col & 7);
            const bf16_t* src = Aimg + ((size_t)((y0 + row) * 66 + col)) * CIN + ci0 + qsrc * 8;
            gld_lds16(src, &ldsA[i * 512]);
        }
    };
    // B tile 64co x 64ci = 512 quads; 2 per thread
    auto stageB = [&](int tap, int ci0, int bufsel) {
        #pragma unroll
        for (int i = 0; i < 2; ++i) {
            int s = (w * 2 + i) * 64 + l;
            int r = s >> 3, qs = s & 7;
            int qsrc = qs ^ (r & 7);
            const bf16_t* src = Wprep + ((size_t)tap * COPAD + cobase + r) * CIN + ci0 + qsrc * 8;
            gld_lds16(src, &ldsB[bufsel][(w * 2 + i) * 512]);
        }
    };

    auto rdA = [&](int dy, int dx, int m, int kk) -> bf16x8 {
        int col = m * 16 + (l & 15) + dx;
        int kq = kk * 4 + (l >> 4);
        float4 v = *(const float4*)&ldsA[((wm + dy) * 66 + col) * 64 + ((kq ^ (col & 7)) * 8)];
        return __builtin_bit_cast(bf16x8, v);
    };
    auto rdB = [&](int bufsel, int n, int kk) -> bf16x8 {
        int r = wn * 32 + n * 16 + (l & 15);
        int kq = kk * 4 + (l >> 4);
        float4 v = *(const float4*)&ldsB[bufsel][r * 64 + ((kq ^ (r & 7)) * 8)];
        return __builtin_bit_cast(bf16x8, v);
    };

    for (int chunk = 0; chunk < NCHUNK; ++chunk) {
        const int ci0 = chunk * 64;
        stageA(ci0);
        stageB(0, ci0, 0);
        __syncthreads();

        int buf = 0;
        for (int tap = 0; tap < 9; ++tap) {
            const int dy = tap / 3, dx = tap % 3;
            if (tap < 8) stageB(tap + 1, ci0, buf ^ 1);
            #pragma unroll
            for (int kk = 0; kk < 2; ++kk) {
                bf16x8 a0 = rdA(dy, dx, 0, kk), a1 = rdA(dy, dx, 1, kk);
                bf16x8 a2 = rdA(dy, dx, 2, kk), a3 = rdA(dy, dx, 3, kk);
                bf16x8 b0 = rdB(buf, 0, kk), b1 = rdB(buf, 1, kk);
                #pragma unroll
                for (int m = 0; m < 4; ++m) {
                    bf16x8 am = (m == 0) ? a0 : (m == 1) ? a1 : (m == 2) ? a2 : a3;
                    if constexpr (MODE == 2) {
                        acc[m][0] = __builtin_amdgcn_mfma_f32_16x16x32_bf16(b0, am, acc[m][0], 0, 0, 0);
                        acc[m][1] = __builtin_amdgcn_mfma_f32_16x16x32_bf16(b1, am, acc[m][1], 0, 0, 0);
                    } else {
                        acc[m][0] = __builtin_amdgcn_mfma_f32_16x16x32_bf16(am, b0, acc[m][0], 0, 0, 0);
                        acc[m][1] = __builtin_amdgcn_mfma_f32_16x16x32_bf16(am, b1, acc[m][1], 0, 0, 0);
                    }
                }
            }
            __syncthreads();
            buf ^= 1;
        }
    }

    #pragma unroll
    for (int m = 0; m < 4; ++m)
        #pragma unroll
        for (int n = 0; n < 2; ++n) {
            f32x4 fr = acc[m][n];
            if constexpr (MODE == 2) {
                int co  = cobase + wn * 32 + n * 16 + (l >> 4) * 4;
                int pix = bx * 128 + wm * 64 + m * 16 + (l & 15);
                float* op = (float*)outp;
                #pragma unroll
                for (int r = 0; r < 4; ++r)
                    op[((size_t)img * 256 + co + r) * HW + pix] = fr[r] + bias0[co + r];
            } else {
                int pix = bx * 128 + wm * 64 + m * 16 + (l >> 4) * 4;
                int co  = cobase + wn * 32 + n * 16 + (l & 15);
                if constexpr (MODE == 0) {
                    bf16_t* op = (bf16_t*)outp;
                    float bv = bias0[co];
                    #pragma unroll
                    for (int r = 0; r < 4; ++r) {
                        int p = pix + r;
                        float vv = fr[r] + bv;
                        if (mask[(size_t)img * HW + p]) vv = 0.f;
                        op[((size_t)img * HW + p) * 256 + co] = (bf16_t)vv;
                    }
                } else {
                    if (co < 288) {
                        f16_t* op = (f16_t*)outp;
                        float bv = (co < 192) ? bias0[co] : bias1[co - 192];
                        #pragma unroll
                        for (int r = 0; r < 4; ++r)
                            op[((size_t)img * HW + pix + r) * 288 + co] = (f16_t)(fr[r] + bv);
                    }
                }
            }
        }
}

// ---------------------------------------------------------------------------
// Deformable sampling core, vectorized gathers, explicit 2-deep pipeline.
// (unchanged from R9)
// ---------------------------------------------------------------------------
__global__ __launch_bounds__(256) void msda_core_kernel(
    const bf16_t* __restrict__ value,
    const f16_t* __restrict__ offattn,
    const float* __restrict__ refp,
    bf16_t* __restrict__ outpad)
{
    constexpr int QB = 16;
    const int n    = blockIdx.y;
    const int q0   = blockIdx.x * QB;
    const int tid  = threadIdx.x;
    const int oct  = tid & 31;
    const int qsub = tid >> 5;
    const int hd   = oct >> 2;

    __shared__ float s_oa[QB][288];
    __shared__ float s_ref[QB][6];
    __shared__ float s_aw[QB][96];

    for (int e = tid; e < QB * 288; e += 256) {
        int q = e / 288, c = e % 288;
        s_oa[q][c] = (float)offattn[((size_t)n * HW + q0 + q) * 288 + c];
    }
    if (tid < QB * 6) {
        int q = tid / 6, r = tid % 6;
        s_ref[q][r] = refp[((size_t)n * HW + q0 + q) * 6 + r];
    }
    __syncthreads();

    if (tid < QB * 8) {
        int q = tid >> 3, h = tid & 7;
        const float* a = &s_oa[q][192 + h * 12];
        float mx = a[0];
        #pragma unroll
        for (int k = 1; k < 12; ++k) mx = fmaxf(mx, a[k]);
        float e[12]; float sum = 0.f;
        #pragma unroll
        for (int k = 0; k < 12; ++k) { e[k] = __expf(a[k] - mx); sum += e[k]; }
        float inv = 1.f / sum;
        #pragma unroll
        for (int k = 0; k < 12; ++k) s_aw[q][h * 12 + k] = e[k] * inv;
    }
    __syncthreads();

    float acc[2][8];
    #pragma unroll
    for (int qi = 0; qi < 2; ++qi)
        #pragma unroll
        for (int j = 0; j < 8; ++j) acc[qi][j] = 0.f;

    const bf16x8 zero8 = {};
    const size_t vstride = (size_t)HW * 256;
    const bf16_t* vimg = value + (size_t)(n * 3) * vstride + oct * 8;

    auto issue = [&](int pt, bf16x8 (&g)[2][4], float (&wt)[2][4]) {
        const int ll = pt >> 2, p = pt & 3;
        const bf16_t* vbase = vimg + (size_t)ll * vstride;
        #pragma unroll
        for (int qi = 0; qi < 2; ++qi) {
            const int qq = qsub * 2 + qi;
            const int idx = hd * 12 + ll * 4 + p;
            float x = s_ref[qq][ll * 2 + 0] * 64.f - 0.5f + s_oa[qq][idx * 2 + 0];
            float y = s_ref[qq][ll * 2 + 1] * 64.f - 0.5f + s_oa[qq][idx * 2 + 1];
            float aw = s_aw[qq][idx];
            float xf = floorf(x), yf = floorf(y);
            float lx = x - xf, ly = y - yf;
            int xi = (int)xf, yi = (int)yf;
            wt[qi][0] = (1.f - lx) * (1.f - ly) * aw;
            wt[qi][1] = lx * (1.f - ly) * aw;
            wt[qi][2] = (1.f - lx) * ly * aw;
            wt[qi][3] = lx * ly * aw;
            bool vx0 = (xi >= 0) && (xi < 64);
            bool vx1 = (xi + 1 >= 0) && (xi + 1 < 64);
            bool vy0 = (yi >= 0) && (yi < 64);
            bool vy1 = (yi + 1 >= 0) && (yi + 1 < 64);
            g[qi][0] = (vy0 && vx0) ? *(const bf16x8*)(vbase + (size_t)(yi * 64 + xi) * 256)           : zero8;
            g[qi][1] = (vy0 && vx1) ? *(const bf16x8*)(vbase + (size_t)(yi * 64 + xi + 1) * 256)       : zero8;
            g[qi][2] = (vy1 && vx0) ? *(const bf16x8*)(vbase + (size_t)((yi + 1) * 64 + xi) * 256)     : zero8;
            g[qi][3] = (vy1 && vx1) ? *(const bf16x8*)(vbase + (size_t)((yi + 1) * 64 + xi + 1) * 256) : zero8;
        }
    };
    auto consume = [&](bf16x8 (&g)[2][4], float (&wt)[2][4]) {
        #pragma unroll
        for (int qi = 0; qi < 2; ++qi)
            #pragma unroll
            for (int j = 0; j < 8; ++j)
                acc[qi][j] += wt[qi][0] * (float)g[qi][0][j] + wt[qi][1] * (float)g[qi][1][j]
                            + wt[qi][2] * (float)g[qi][2][j] + wt[qi][3] * (float)g[qi][3][j];
    };

    bf16x8 gA[2][4], gB[2][4];
    float  wA[2][4], wB[2][4];
    issue(0, gA, wA);
    #pragma unroll 1
    for (int pt = 0; pt < 12; pt += 2) {
        if (pt + 1 < 12) issue(pt + 1, gB, wB);
        consume(gA, wA);
        if (pt + 2 < 12) issue(pt + 2, gA, wA);
        consume(gB, wB);
    }

    #pragma unroll
    for (int qi = 0; qi < 2; ++qi) {
        const int qq = qsub * 2 + qi;
        int pix = q0 + qq;
        int pp = ((pix >> 6) + 1) * 66 + (pix & 63) + 1;
        bf16_t tmp[8];
        #pragma unroll
        for (int j = 0; j < 8; ++j) tmp[j] = (bf16_t)acc[qi][j];
        *(bf16x8*)&outpad[((size_t)n * 4356 + pp) * 256 + oct * 8] = *(bf16x8*)tmp;
    }
}

extern "C" void kernel_launch(void* const* d_in, const int* in_sizes, int n_in,
                              void* d_out, int out_size, void* d_ws, size_t ws_size,
                              hipStream_t stream) {
    const float* query   = (const float*)d_in[0];
    const float* refp    = (const float*)d_in[1];
    const float* inflat  = (const float*)d_in[2];
    const unsigned char* mask = (const unsigned char*)d_in[5];
    const float* w_value = (const float*)d_in[6];
    const float* b_value = (const float*)d_in[7];
    const float* w_off   = (const float*)d_in[8];
    const float* b_off   = (const float*)d_in[9];
    const float* w_attn  = (const float*)d_in[10];
    const float* b_attn  = (const float*)d_in[11];
    const float* w_out   = (const float*)d_in[12];
    const float* b_out   = (const float*)d_in[13];

    char* ws = (char*)d_ws;
    bf16_t* A_val  = (bf16_t*)ws;  ws += (size_t)12 * 4356 * 256 * 2;  // 26.76 MB
    bf16_t* A_qry  = (bf16_t*)ws;  ws += (size_t)4 * 4356 * 768 * 2;   // 26.76 MB
    bf16_t* A_core = (bf16_t*)ws;  ws += (size_t)4 * 4356 * 256 * 2;   // 8.92 MB
    bf16_t* W_val  = (bf16_t*)ws;  ws += (size_t)9 * 256 * 256 * 2;
    bf16_t* W_off  = (bf16_t*)ws;  ws += (size_t)9 * 320 * 768 * 2;    // COPAD=320
    bf16_t* W_out  = (bf16_t*)ws;  ws += (size_t)9 * 256 * 256 * 2;
    f16_t*  offattn = (f16_t*)ws;  ws += (size_t)4 * 4096 * 288 * 2;   // 9.44 MB
    bf16_t* value  = A_qry;  // reuse: off-conv consumes A_qry before value conv writes
    // total ws ~ 79.6 MiB (< 86 MiB proven available by round 1)

    // R14: zero only the 260 border cells per padded image (~3.7MB) instead
    // of the 71MB full memset; interiors are fully rewritten every call.
    zero_border<<<dim3(33, 12), 256, 0, stream>>>(A_val, 256);
    zero_border<<<dim3(98, 4),  256, 0, stream>>>(A_qry, 768);
    zero_border<<<dim3(33, 4),  256, 0, stream>>>(A_core, 256);

    prep_w<<<(256 * 256 + 255) / 256, 256, 0, stream>>>(w_value, nullptr, W_val, 256, 256, 256, 256);
    prep_w<<<(320 * 768 + 255) / 256, 256, 0, stream>>>(w_off, w_attn, W_off, 768, 192, 288, 320);
    prep_w<<<(256 * 256 + 255) / 256, 256, 0, stream>>>(w_out, nullptr, W_out, 256, 256, 256, 256);

    pad_nchw_to_nhwc<<<dim3(64, 4, 12), 256, 0, stream>>>(inflat, A_val, 256);
    pad_nchw_to_nhwc<<<dim3(64, 12, 4), 256, 0, stream>>>(query,  A_qry, 768);

    mfma_conv<768, 1><<<dim3(32, 5, 4),  256, 0, stream>>>(A_qry, W_off, b_off, b_attn, nullptr, offattn);
    mfma_conv<256, 0><<<dim3(32, 4, 12), 256, 0, stream>>>(A_val, W_val, b_value, nullptr, mask, value);

    msda_core_kernel<<<dim3(HW / 16, 4), 256, 0, stream>>>(value, offattn, refp, A_core);

    mfma_conv<256, 2><<<dim3(32, 4, 4),  256, 0, stream>>>(A_core, W_out, b_out, nullptr, nullptr, d_out);
}